// Round 2
// baseline (361.521 us; speedup 1.0000x reference)
//
#include <hip/hip_runtime.h>
#include <hip/hip_bf16.h>
#include <math.h>

#define EPSV 1e-6f

typedef __attribute__((ext_vector_type(8))) short bf16x8;
typedef __attribute__((ext_vector_type(4))) float f32x4;
typedef __attribute__((ext_vector_type(4))) unsigned short u16x4;

__device__ inline float bf2f(unsigned short u) {
  union { unsigned int i; float f; } v;
  v.i = ((unsigned int)u) << 16;
  return v.f;
}
// RNE bf16 round, no NaN path (all values finite here)
__device__ inline unsigned short f2bf(float f) {
  unsigned int u = __builtin_bit_cast(unsigned int, f);
  u += 0x7FFFu + ((u >> 16) & 1u);
  return (unsigned short)(u >> 16);
}
// tanh-GELU via exp + hw rcp (no div sequence)
__device__ inline float fast_gelu(float v) {
  float u = 1.5957691216057308f * (v + 0.044715f * v * v * v);
  float t = __expf(-u);
  return v * __builtin_amdgcn_rcpf(1.f + t);
}

// ---- Kernel 0: pack all weights into MFMA B-fragment layout (bf16) ----
// B-frag: [ntile][kstep][lane][8], n=ntile*16+(lane&15), k=kstep*32+(lane>>4)*8+j
__global__ __launch_bounds__(256) void k0_pack(
    const float* __restrict__ qw, const float* __restrict__ aw,
    const float* __restrict__ w1, const float* __restrict__ w2,
    const float* __restrict__ pw, unsigned short* __restrict__ qwp,
    unsigned short* __restrict__ awp, unsigned short* __restrict__ w1p,
    unsigned short* __restrict__ w2p, unsigned short* __restrict__ pwp) {
  int idx = blockIdx.x * 256 + threadIdx.x;
  int lane = idx & 63;
  int l15 = lane & 15, quad = lane >> 4;
  if (idx < 6912) {
    int fi = idx >> 6;
    int ntile = fi / 3, kstep = fi - ntile * 3;
    int n = ntile * 16 + l15, k0 = kstep * 32 + quad * 8;
#pragma unroll
    for (int j = 0; j < 8; ++j)
      qwp[(size_t)idx * 8 + j] = f2bf(qw[(size_t)(k0 + j) * 576 + n]);
  } else if (idx < 11520) {
    int i2 = idx - 6912;
    int fi = i2 >> 6;
    int ntile = fi / 6, kstep = fi - ntile * 6;
    int n = ntile * 16 + l15, k0 = kstep * 32 + quad * 8;
#pragma unroll
    for (int j = 0; j < 8; ++j)
      awp[(size_t)i2 * 8 + j] = f2bf(aw[(size_t)(k0 + j) * 192 + n]);
  } else if (idx < 29952) {
    int i3 = idx - 11520;
    int fi = i3 >> 6;
    int ntile = fi / 6, kstep = fi - ntile * 6;
    int n = ntile * 16 + l15, k0 = kstep * 32 + quad * 8;
#pragma unroll
    for (int j = 0; j < 8; ++j)
      w1p[(size_t)i3 * 8 + j] = f2bf(w1[(size_t)(k0 + j) * 768 + n]);
  } else if (idx < 48384) {
    int i4 = idx - 29952;
    int fi = i4 >> 6;
    int ntile = fi / 24, kstep = fi - ntile * 24;
    int n = ntile * 16 + l15, k0 = kstep * 32 + quad * 8;
#pragma unroll
    for (int j = 0; j < 8; ++j)
      w2p[(size_t)i4 * 8 + j] = f2bf(w2[(size_t)(k0 + j) * 192 + n]);
  } else if (idx < 50688) {
    int i5 = idx - 48384;
    int fi = i5 >> 6;
    int ntile = fi / 3, kstep = fi - ntile * 3;
    int n = ntile * 16 + l15, k0 = kstep * 32 + quad * 8;
#pragma unroll
    for (int j = 0; j < 8; ++j)
      pwp[(size_t)i5 * 8 + j] = f2bf(pw[(size_t)(k0 + j) * 192 + n]);
  }
}

// -- Kernel 1234: the whole block fused, one block per 8x8 window ----------
// LN1 -> proj/maxpool shortcut -> qkv -> windowed attn -> attn_proj ->
// y = shortcut+attn (LDS) -> LN2 -> MLP -> out = y + mlp  (single store).
// LDS aliasing: xn lives in kk's bytes (dead at S2, kk written after S2);
// yn/hls live in vT's bytes (vT dead after PV / B2).
__global__ __launch_bounds__(256) void k1234_fused(
    const float* __restrict__ x, const float* __restrict__ n1g,
    const float* __restrict__ n1b, const unsigned short* __restrict__ pwp,
    const float* __restrict__ pb, const unsigned short* __restrict__ qwp,
    const float* __restrict__ qb, const unsigned short* __restrict__ awp,
    const float* __restrict__ ab, const float* __restrict__ n2g,
    const float* __restrict__ n2b, const unsigned short* __restrict__ w1p,
    const float* __restrict__ b1, const unsigned short* __restrict__ w2p,
    const float* __restrict__ b2, float* __restrict__ out) {
  __shared__ __align__(16) unsigned char smem[72960];
  unsigned short (*kk)[200] = (unsigned short (*)[200])smem;        // 25,600 B: xn -> K -> obb
  unsigned short (*vT)[72] = (unsigned short (*)[72])(smem + 25600); // 27,648 B: V^T -> yn/hls
  unsigned short (*wbuf)[16][72] =
      (unsigned short (*)[16][72])(smem + 53248);                    //  6,912 B: pooled Q -> P
  float (*sc)[200] = (float (*)[200])(smem + 60160);                 // 12,800 B: shortcut -> y
  unsigned short (*yn)[196] = (unsigned short (*)[196])(smem + 25600);        // alias vT
  unsigned short (*hls)[196] = (unsigned short (*)[196])(smem + 25600 + 6272); // alias vT

  int tid = threadIdx.x, wave = tid >> 6, lane = tid & 63;
  int wi = blockIdx.x;
  int b = wi >> 10, nh = (wi >> 5) & 31, nw = wi & 31;
  int grow0 = nh * 8, gcol0 = nw * 8;
  int l15 = lane & 15, quad = lane >> 4;

  // ---- LN1: token tt (0..63) handled by 4 threads (sub 0..3) ----
  {
    int tt = tid >> 2, sub = tid & 3;
    int rr = tt >> 3, cc = tt & 7;
    size_t tok = (size_t)((b * 256 + grow0 + rr) * 256 + gcol0 + cc);
    const f32x4* xr4 = (const f32x4*)(x + tok * 96 + sub * 24);
    f32x4 v[6];
#pragma unroll
    for (int i = 0; i < 6; ++i) v[i] = xr4[i];
    float s = 0.f;
#pragma unroll
    for (int i = 0; i < 6; ++i)
#pragma unroll
      for (int j = 0; j < 4; ++j) s += v[i][j];
    s += __shfl_xor(s, 1);
    s += __shfl_xor(s, 2);
    float mean = s * (1.f / 96.f);
    float q = 0.f;
#pragma unroll
    for (int i = 0; i < 6; ++i)
#pragma unroll
      for (int j = 0; j < 4; ++j) {
        float d = v[i][j] - mean;
        q += d * d;
      }
    q += __shfl_xor(q, 1);
    q += __shfl_xor(q, 2);
    float rstd = rsqrtf(q * (1.f / 96.f) + EPSV);
    const f32x4* g4 = (const f32x4*)(n1g + sub * 24);
    const f32x4* b4 = (const f32x4*)(n1b + sub * 24);
#pragma unroll
    for (int i = 0; i < 6; ++i) {
      f32x4 gg = g4[i], bb = b4[i];
      u16x4 o;
#pragma unroll
      for (int j = 0; j < 4; ++j)
        o[j] = f2bf((v[i][j] - mean) * rstd * gg[j] + bb[j]);
      *(u16x4*)(&kk[tt][sub * 24 + i * 4]) = o;  // xn aliased into kk
    }
  }
  __syncthreads();  // S1: xn visible

  // A-frags (xw 64x96) from LDS; m = token index (row-major in window)
  bf16x8 areg[4][3];
#pragma unroll
  for (int mt = 0; mt < 4; ++mt)
#pragma unroll
    for (int ks = 0; ks < 3; ++ks)
      areg[mt][ks] = *(const bf16x8*)(&kk[mt * 16 + l15][ks * 32 + quad * 8]);
  __syncthreads();  // S2: xn dead everywhere -> kk may be overwritten (qkv)

  // ---- proj + maxpool2x2 -> shortcut (f32 in LDS) ----
#pragma unroll
  for (int nl = 0; nl < 3; ++nl) {
    int nt = wave * 3 + nl;
    const unsigned short* bp = pwp + ((size_t)(nt * 3) * 64 + lane) * 8;
    bf16x8 b0 = *(const bf16x8*)(bp);
    bf16x8 b1v = *(const bf16x8*)(bp + 512);
    bf16x8 b2v = *(const bf16x8*)(bp + 1024);
    int c = nt * 16 + l15;
    float bias = pb[c];
#pragma unroll
    for (int mt = 0; mt < 4; ++mt) {
      f32x4 acc = {0.f, 0.f, 0.f, 0.f};
      acc = __builtin_amdgcn_mfma_f32_16x16x32_bf16(areg[mt][0], b0, acc, 0, 0, 0);
      acc = __builtin_amdgcn_mfma_f32_16x16x32_bf16(areg[mt][1], b1v, acc, 0, 0, 0);
      acc = __builtin_amdgcn_mfma_f32_16x16x32_bf16(areg[mt][2], b2v, acc, 0, 0, 0);
      float p0 = fmaxf(acc[0], acc[1]);
      float p1 = fmaxf(acc[2], acc[3]);
      float q0 = fmaxf(p0, __shfl_xor(p0, 32));
      float q1 = fmaxf(p1, __shfl_xor(p1, 32));
      if (quad < 2) {
        int p = mt * 4 + quad * 2;
        sc[p][c] = q0 + bias;
        sc[p + 1][c] = q1 + bias;
      }
    }
  }

  // ---- Phase 1: qkv GEMM, 9 ntile-jobs per wave ----
#pragma unroll
  for (int aj = 0; aj < 9; ++aj) {
    int type, hh, nt;
    if (wave < 3) {
      if (aj < 4) { type = 0; hh = wave; nt = aj; }
      else { int kv = wave * 5 + (aj - 4); type = 1 + kv / 12; int t2 = kv % 12; hh = t2 >> 2; nt = t2 & 3; }
    } else {
      int kv = 15 + aj; type = 1 + kv / 12; int t2 = kv % 12; hh = t2 >> 2; nt = t2 & 3;
    }
    int gnt = type * 12 + hh * 4 + nt;
    const unsigned short* bp = qwp + (size_t)gnt * 1536 + lane * 8;
    bf16x8 b0 = *(const bf16x8*)(bp);
    bf16x8 b1v = *(const bf16x8*)(bp + 512);
    bf16x8 b2v = *(const bf16x8*)(bp + 1024);
    int dloc = nt * 16 + l15;
    int dglob = hh * 64 + dloc;
    float bias = qb[type * 192 + dglob];
#pragma unroll
    for (int mt = 0; mt < 4; ++mt) {
      f32x4 acc = {0.f, 0.f, 0.f, 0.f};
      acc = __builtin_amdgcn_mfma_f32_16x16x32_bf16(areg[mt][0], b0, acc, 0, 0, 0);
      acc = __builtin_amdgcn_mfma_f32_16x16x32_bf16(areg[mt][1], b1v, acc, 0, 0, 0);
      acc = __builtin_amdgcn_mfma_f32_16x16x32_bf16(areg[mt][2], b2v, acc, 0, 0, 0);
      if (type == 0) {
        float p0 = fmaxf(acc[0], acc[1]);
        float p1 = fmaxf(acc[2], acc[3]);
        float q0 = fmaxf(p0, __shfl_xor(p0, 32));
        float q1 = fmaxf(p1, __shfl_xor(p1, 32));
        if (quad < 2) {
          int p = mt * 4 + quad * 2;
          wbuf[wave][p][dloc] = f2bf(q0 + bias);  // pooled Q, wave-private
          wbuf[wave][p + 1][dloc] = f2bf(q1 + bias);
        }
      } else if (type == 1) {
        int t0 = mt * 16 + quad * 4;
#pragma unroll
        for (int r = 0; r < 4; ++r) kk[t0 + r][dglob] = f2bf(acc[r] + bias);
      } else {
        int t0 = mt * 16 + quad * 4;
        u16x4 pk;
#pragma unroll
        for (int r = 0; r < 4; ++r) pk[r] = f2bf(acc[r] + bias);
        *(u16x4*)(&vT[dglob][t0]) = pk;
      }
    }
  }
  __syncthreads();  // B1: kk/vT visible to all waves

  // ---- Phase 2: wave h owns head h ----
  f32x4 o4[4];
  if (wave < 3) {
    int h = wave;
    bf16x8 aq0 = *(const bf16x8*)(&wbuf[wave][l15][quad * 8]);
    bf16x8 aq1 = *(const bf16x8*)(&wbuf[wave][l15][32 + quad * 8]);
    f32x4 s4[4];
#pragma unroll
    for (int kt = 0; kt < 4; ++kt) {
      bf16x8 bk0 = *(const bf16x8*)(&kk[kt * 16 + l15][h * 64 + quad * 8]);
      bf16x8 bk1 = *(const bf16x8*)(&kk[kt * 16 + l15][h * 64 + 32 + quad * 8]);
      f32x4 s = {0.f, 0.f, 0.f, 0.f};
      s = __builtin_amdgcn_mfma_f32_16x16x32_bf16(aq0, bk0, s, 0, 0, 0);
      s = __builtin_amdgcn_mfma_f32_16x16x32_bf16(aq1, bk1, s, 0, 0, 0);
      s4[kt] = s;
    }
    // in-register softmax over 64 keys
    float ps[4][4];
#pragma unroll
    for (int r = 0; r < 4; ++r) {
      float m = fmaxf(fmaxf(s4[0][r], s4[1][r]), fmaxf(s4[2][r], s4[3][r]));
#pragma unroll
      for (int o = 8; o; o >>= 1) m = fmaxf(m, __shfl_xor(m, o));
      float sm = 0.f;
#pragma unroll
      for (int kt = 0; kt < 4; ++kt) {
        float e = __expf((s4[kt][r] - m) * 0.125f);
        ps[kt][r] = e;
        sm += e;
      }
#pragma unroll
      for (int o = 8; o; o >>= 1) sm += __shfl_xor(sm, o);
      float inv = __builtin_amdgcn_rcpf(sm);
#pragma unroll
      for (int kt = 0; kt < 4; ++kt) ps[kt][r] *= inv;
    }
    // P -> A-layout via wave-private LDS (overwrites pooled Q; aq in regs)
#pragma unroll
    for (int kt = 0; kt < 4; ++kt)
#pragma unroll
      for (int r = 0; r < 4; ++r)
        wbuf[wave][quad * 4 + r][kt * 16 + l15] = f2bf(ps[kt][r]);
    bf16x8 ap0 = *(const bf16x8*)(&wbuf[wave][l15][quad * 8]);
    bf16x8 ap1 = *(const bf16x8*)(&wbuf[wave][l15][32 + quad * 8]);
#pragma unroll
    for (int dt = 0; dt < 4; ++dt) {
      bf16x8 bv0 = *(const bf16x8*)(&vT[h * 64 + dt * 16 + l15][quad * 8]);
      bf16x8 bv1 = *(const bf16x8*)(&vT[h * 64 + dt * 16 + l15][32 + quad * 8]);
      f32x4 o = {0.f, 0.f, 0.f, 0.f};
      o = __builtin_amdgcn_mfma_f32_16x16x32_bf16(ap0, bv0, o, 0, 0, 0);
      o = __builtin_amdgcn_mfma_f32_16x16x32_bf16(ap1, bv1, o, 0, 0, 0);
      o4[dt] = o;
    }
  }
  __syncthreads();  // B2: kk/vT reads done -> kk reusable for obb, vT for yn/hls

  if (wave < 3) {
    int h = wave;
#pragma unroll
    for (int dt = 0; dt < 4; ++dt)
#pragma unroll
      for (int r = 0; r < 4; ++r)
        kk[quad * 4 + r][h * 64 + dt * 16 + l15] = f2bf(o4[dt][r]);  // obb
  }
  __syncthreads();  // B3: obb readable

  // ---- attn_proj: O(16x192) @ aw + ab; y = shortcut + attn into sc ----
  bf16x8 ao[6];
#pragma unroll
  for (int ks = 0; ks < 6; ++ks)
    ao[ks] = *(const bf16x8*)(&kk[l15][ks * 32 + quad * 8]);
#pragma unroll
  for (int nl = 0; nl < 3; ++nl) {
    int ntl = wave * 3 + nl;
    const unsigned short* bp = awp + (size_t)ntl * 3072 + lane * 8;
    f32x4 acc = {0.f, 0.f, 0.f, 0.f};
#pragma unroll
    for (int ks = 0; ks < 6; ++ks) {
      bf16x8 bw = *(const bf16x8*)(bp + ks * 512);
      acc = __builtin_amdgcn_mfma_f32_16x16x32_bf16(ao[ks], bw, acc, 0, 0, 0);
    }
    int cc = ntl * 16 + l15;
    float bias = ab[cc];
#pragma unroll
    for (int r = 0; r < 4; ++r) {
      int p = quad * 4 + r;
      sc[p][cc] += acc[r] + bias;  // unique (p,cc) per thread
    }
  }
  __syncthreads();  // B4: y complete in sc; vT dead -> yn/hls writable

  // ---- LN2 on the 16 pooled tokens (16 lanes per token, 12 ch each) ----
  {
    int tt = wave * 4 + quad;  // 0..15
    const f32x4* y4 = (const f32x4*)(&sc[tt][l15 * 12]);
    f32x4 vv[3];
    vv[0] = y4[0]; vv[1] = y4[1]; vv[2] = y4[2];
    float s = 0.f;
#pragma unroll
    for (int i = 0; i < 3; ++i)
#pragma unroll
      for (int j = 0; j < 4; ++j) s += vv[i][j];
    s += __shfl_xor(s, 1);
    s += __shfl_xor(s, 2);
    s += __shfl_xor(s, 4);
    s += __shfl_xor(s, 8);
    float mean = s * (1.f / 192.f);
    float q = 0.f;
#pragma unroll
    for (int i = 0; i < 3; ++i)
#pragma unroll
      for (int j = 0; j < 4; ++j) {
        float d = vv[i][j] - mean;
        q += d * d;
      }
    q += __shfl_xor(q, 1);
    q += __shfl_xor(q, 2);
    q += __shfl_xor(q, 4);
    q += __shfl_xor(q, 8);
    float rstd = rsqrtf(q * (1.f / 192.f) + EPSV);
    const f32x4* g4 = (const f32x4*)(n2g + l15 * 12);
    const f32x4* b4 = (const f32x4*)(n2b + l15 * 12);
#pragma unroll
    for (int i = 0; i < 3; ++i) {
      f32x4 gg = g4[i], bb = b4[i];
      u16x4 o;
#pragma unroll
      for (int j = 0; j < 4; ++j)
        o[j] = f2bf((vv[i][j] - mean) * rstd * gg[j] + bb[j]);
      *(u16x4*)(&yn[tt][l15 * 12 + i * 4]) = o;
    }
  }
  __syncthreads();  // B5: yn ready

  // ---- MLP: 16x192 -> 768 (gelu) -> 192, 4 hidden chunks of 192 ----
  bf16x8 ar[6];
#pragma unroll
  for (int ks = 0; ks < 6; ++ks)
    ar[ks] = *(const bf16x8*)(&yn[l15][ks * 32 + quad * 8]);

  f32x4 acc2[3];
#pragma unroll
  for (int nl = 0; nl < 3; ++nl) acc2[nl] = (f32x4){0.f, 0.f, 0.f, 0.f};

  for (int c = 0; c < 4; ++c) {
#pragma unroll
    for (int nl = 0; nl < 3; ++nl) {
      int gnt = c * 12 + wave * 3 + nl;
      const unsigned short* bp = w1p + ((size_t)(gnt * 6) * 64 + lane) * 8;
      f32x4 t0 = {0.f, 0.f, 0.f, 0.f};
#pragma unroll
      for (int ks = 0; ks < 6; ++ks) {
        bf16x8 bw = *(const bf16x8*)(bp + ks * 512);
        t0 = __builtin_amdgcn_mfma_f32_16x16x32_bf16(ar[ks], bw, t0, 0, 0, 0);
      }
      int lcol = wave * 48 + nl * 16 + l15;
      float bias = b1[c * 192 + lcol];
#pragma unroll
      for (int r = 0; r < 4; ++r)
        hls[quad * 4 + r][lcol] = f2bf(fast_gelu(t0[r] + bias));
    }
    __syncthreads();  // hls chunk ready
    bf16x8 hr[6];
#pragma unroll
    for (int ks = 0; ks < 6; ++ks)
      hr[ks] = *(const bf16x8*)(&hls[l15][ks * 32 + quad * 8]);
#pragma unroll
    for (int nl = 0; nl < 3; ++nl) {
      int nt2 = wave * 3 + nl;
      const unsigned short* bp =
          w2p + ((size_t)(nt2 * 24 + c * 6) * 64 + lane) * 8;
#pragma unroll
      for (int ks = 0; ks < 6; ++ks) {
        bf16x8 bw = *(const bf16x8*)(bp + ks * 512);
        acc2[nl] =
            __builtin_amdgcn_mfma_f32_16x16x32_bf16(hr[ks], bw, acc2[nl], 0, 0, 0);
      }
    }
    __syncthreads();  // hls readers done -> next chunk may overwrite
  }

  // ---- epilogue: out = y + mlp + b2, pure store ----
#pragma unroll
  for (int nl = 0; nl < 3; ++nl) {
    int col = (wave * 3 + nl) * 16 + l15;
    float bias = b2[col];
#pragma unroll
    for (int r = 0; r < 4; ++r) {
      int p = quad * 4 + r;
      int hp = nh * 4 + (p >> 2), wp2 = nw * 4 + (p & 3);
      size_t oi = ((size_t)((b * 128 + hp) * 128 + wp2)) * 192 + col;
      out[oi] = sc[p][col] + acc2[nl][r] + bias;
    }
  }
}

extern "C" void kernel_launch(void* const* d_in, const int* in_sizes, int n_in,
                              void* d_out, int out_size, void* d_ws,
                              size_t ws_size, hipStream_t stream) {
  const float* x = (const float*)d_in[0];
  const float* n1g = (const float*)d_in[1];
  const float* n1b = (const float*)d_in[2];
  const float* pw = (const float*)d_in[3];
  const float* pb = (const float*)d_in[4];
  const float* qw = (const float*)d_in[5];
  const float* qb = (const float*)d_in[6];
  const float* aw = (const float*)d_in[7];
  const float* ab = (const float*)d_in[8];
  const float* n2g = (const float*)d_in[9];
  const float* n2b = (const float*)d_in[10];
  const float* w1 = (const float*)d_in[11];
  const float* b1 = (const float*)d_in[12];
  const float* w2 = (const float*)d_in[13];
  const float* b2 = (const float*)d_in[14];
  float* out = (float*)d_out;

  char* wsb = (char*)d_ws;
  unsigned short* qwp = (unsigned short*)wsb;               //    110,592 B
  unsigned short* awp = (unsigned short*)(wsb + 110592);    //     73,728 B
  unsigned short* w1p = (unsigned short*)(wsb + 184320);    //    294,912 B
  unsigned short* w2p = (unsigned short*)(wsb + 479232);    //    294,912 B
  unsigned short* pwp = (unsigned short*)(wsb + 774144);    //     36,864 B

  hipLaunchKernelGGL(k0_pack, dim3(198), dim3(256), 0, stream, qw, aw, w1, w2,
                     pw, qwp, awp, w1p, w2p, pwp);
  hipLaunchKernelGGL(k1234_fused, dim3(4096), dim3(256), 0, stream, x, n1g,
                     n1b, pwp, pb, qwp, qb, awp, ab, n2g, n2b, w1p, b1, w2p,
                     b2, out);
}

// Round 3
// 317.792 us; speedup vs baseline: 1.1376x; 1.1376x over previous
//
#include <hip/hip_runtime.h>
#include <hip/hip_bf16.h>
#include <math.h>

#define EPSV 1e-6f

typedef __attribute__((ext_vector_type(8))) short bf16x8;
typedef __attribute__((ext_vector_type(4))) float f32x4;
typedef __attribute__((ext_vector_type(4))) unsigned short u16x4;

__device__ inline float bf2f(unsigned short u) {
  union { unsigned int i; float f; } v;
  v.i = ((unsigned int)u) << 16;
  return v.f;
}
// RNE bf16 round, no NaN path (all values finite here)
__device__ inline unsigned short f2bf(float f) {
  unsigned int u = __builtin_bit_cast(unsigned int, f);
  u += 0x7FFFu + ((u >> 16) & 1u);
  return (unsigned short)(u >> 16);
}
// tanh-GELU via exp + hw rcp (no div sequence)
__device__ inline float fast_gelu(float v) {
  float u = 1.5957691216057308f * (v + 0.044715f * v * v * v);
  float t = __expf(-u);
  return v * __builtin_amdgcn_rcpf(1.f + t);
}

// ---- Kernel 0: pack all weights into MFMA B-fragment layout (bf16) ----
// B-frag: [ntile][kstep][lane][8], n=ntile*16+(lane&15), k=kstep*32+(lane>>4)*8+j
__global__ __launch_bounds__(256) void k0_pack(
    const float* __restrict__ qw, const float* __restrict__ aw,
    const float* __restrict__ w1, const float* __restrict__ w2,
    const float* __restrict__ pw, unsigned short* __restrict__ qwp,
    unsigned short* __restrict__ awp, unsigned short* __restrict__ w1p,
    unsigned short* __restrict__ w2p, unsigned short* __restrict__ pwp) {
  int idx = blockIdx.x * 256 + threadIdx.x;
  int lane = idx & 63;
  int l15 = lane & 15, quad = lane >> 4;
  if (idx < 6912) {
    int fi = idx >> 6;
    int ntile = fi / 3, kstep = fi - ntile * 3;
    int n = ntile * 16 + l15, k0 = kstep * 32 + quad * 8;
#pragma unroll
    for (int j = 0; j < 8; ++j)
      qwp[(size_t)idx * 8 + j] = f2bf(qw[(size_t)(k0 + j) * 576 + n]);
  } else if (idx < 11520) {
    int i2 = idx - 6912;
    int fi = i2 >> 6;
    int ntile = fi / 6, kstep = fi - ntile * 6;
    int n = ntile * 16 + l15, k0 = kstep * 32 + quad * 8;
#pragma unroll
    for (int j = 0; j < 8; ++j)
      awp[(size_t)i2 * 8 + j] = f2bf(aw[(size_t)(k0 + j) * 192 + n]);
  } else if (idx < 29952) {
    int i3 = idx - 11520;
    int fi = i3 >> 6;
    int ntile = fi / 6, kstep = fi - ntile * 6;
    int n = ntile * 16 + l15, k0 = kstep * 32 + quad * 8;
#pragma unroll
    for (int j = 0; j < 8; ++j)
      w1p[(size_t)i3 * 8 + j] = f2bf(w1[(size_t)(k0 + j) * 768 + n]);
  } else if (idx < 48384) {
    int i4 = idx - 29952;
    int fi = i4 >> 6;
    int ntile = fi / 24, kstep = fi - ntile * 24;
    int n = ntile * 16 + l15, k0 = kstep * 32 + quad * 8;
#pragma unroll
    for (int j = 0; j < 8; ++j)
      w2p[(size_t)i4 * 8 + j] = f2bf(w2[(size_t)(k0 + j) * 192 + n]);
  } else if (idx < 50688) {
    int i5 = idx - 48384;
    int fi = i5 >> 6;
    int ntile = fi / 3, kstep = fi - ntile * 3;
    int n = ntile * 16 + l15, k0 = kstep * 32 + quad * 8;
#pragma unroll
    for (int j = 0; j < 8; ++j)
      pwp[(size_t)i5 * 8 + j] = f2bf(pw[(size_t)(k0 + j) * 192 + n]);
  }
}

// -- Kernel 1234: whole block fused; K/V phase-split shares one LDS buffer --
// LDS (46,848 B -> 3 blocks/CU):
//   buf1 @0      (27,648): xn -> K[64][200] -> V^T[192][72] -> obb[16][200]
//                          (+yn @6400, hls @12800 after V dead)
//   wbuf @27,648 ( 6,912): per-wave pooled Q -> P
//   sc   @34,560 (12,288): f32 shortcut -> y [16][192]
__global__ __launch_bounds__(256) void k1234_fused(
    const float* __restrict__ x, const float* __restrict__ n1g,
    const float* __restrict__ n1b, const unsigned short* __restrict__ pwp,
    const float* __restrict__ pb, const unsigned short* __restrict__ qwp,
    const float* __restrict__ qb, const unsigned short* __restrict__ awp,
    const float* __restrict__ ab, const float* __restrict__ n2g,
    const float* __restrict__ n2b, const unsigned short* __restrict__ w1p,
    const float* __restrict__ b1, const unsigned short* __restrict__ w2p,
    const float* __restrict__ b2, float* __restrict__ out) {
  __shared__ __align__(16) unsigned char smem[46848];
  unsigned short (*kk)[200] = (unsigned short (*)[200])smem;   // xn/K/obb
  unsigned short (*vT)[72] = (unsigned short (*)[72])smem;     // V^T (after B1.5)
  unsigned short (*wbuf)[16][72] =
      (unsigned short (*)[16][72])(smem + 27648);
  float (*sc)[192] = (float (*)[192])(smem + 34560);
  unsigned short (*yn)[200] = (unsigned short (*)[200])(smem + 6400);
  unsigned short (*hls)[200] = (unsigned short (*)[200])(smem + 12800);

  int tid = threadIdx.x, wave = tid >> 6, lane = tid & 63;
  int wi = blockIdx.x;
  int b = wi >> 10, nh = (wi >> 5) & 31, nw = wi & 31;
  int grow0 = nh * 8, gcol0 = nw * 8;
  int l15 = lane & 15, quad = lane >> 4;

  // ---- LN1: token tt (0..63) handled by 4 threads (sub 0..3) ----
  {
    int tt = tid >> 2, sub = tid & 3;
    int rr = tt >> 3, cc = tt & 7;
    size_t tok = (size_t)((b * 256 + grow0 + rr) * 256 + gcol0 + cc);
    const f32x4* xr4 = (const f32x4*)(x + tok * 96 + sub * 24);
    f32x4 v[6];
#pragma unroll
    for (int i = 0; i < 6; ++i) v[i] = xr4[i];
    float s = 0.f;
#pragma unroll
    for (int i = 0; i < 6; ++i)
#pragma unroll
      for (int j = 0; j < 4; ++j) s += v[i][j];
    s += __shfl_xor(s, 1);
    s += __shfl_xor(s, 2);
    float mean = s * (1.f / 96.f);
    float q = 0.f;
#pragma unroll
    for (int i = 0; i < 6; ++i)
#pragma unroll
      for (int j = 0; j < 4; ++j) {
        float d = v[i][j] - mean;
        q += d * d;
      }
    q += __shfl_xor(q, 1);
    q += __shfl_xor(q, 2);
    float rstd = rsqrtf(q * (1.f / 96.f) + EPSV);
    const f32x4* g4 = (const f32x4*)(n1g + sub * 24);
    const f32x4* b4 = (const f32x4*)(n1b + sub * 24);
#pragma unroll
    for (int i = 0; i < 6; ++i) {
      f32x4 gg = g4[i], bb = b4[i];
      u16x4 o;
#pragma unroll
      for (int j = 0; j < 4; ++j)
        o[j] = f2bf((v[i][j] - mean) * rstd * gg[j] + bb[j]);
      *(u16x4*)(&kk[tt][sub * 24 + i * 4]) = o;  // xn aliased into kk
    }
  }
  __syncthreads();  // S1: xn visible

  // A-frags (xw 64x96) from LDS; m = token index (row-major in window)
  bf16x8 areg[4][3];
#pragma unroll
  for (int mt = 0; mt < 4; ++mt)
#pragma unroll
    for (int ks = 0; ks < 3; ++ks)
      areg[mt][ks] = *(const bf16x8*)(&kk[mt * 16 + l15][ks * 32 + quad * 8]);
  __syncthreads();  // S2: xn dead -> kk writable (K)

  // ---- proj + maxpool2x2 -> shortcut (f32 in LDS) ----
#pragma unroll
  for (int nl = 0; nl < 3; ++nl) {
    int nt = wave * 3 + nl;
    const unsigned short* bp = pwp + ((size_t)(nt * 3) * 64 + lane) * 8;
    bf16x8 b0 = *(const bf16x8*)(bp);
    bf16x8 b1v = *(const bf16x8*)(bp + 512);
    bf16x8 b2v = *(const bf16x8*)(bp + 1024);
    int c = nt * 16 + l15;
    float bias = pb[c];
#pragma unroll
    for (int mt = 0; mt < 4; ++mt) {
      f32x4 acc = {0.f, 0.f, 0.f, 0.f};
      acc = __builtin_amdgcn_mfma_f32_16x16x32_bf16(areg[mt][0], b0, acc, 0, 0, 0);
      acc = __builtin_amdgcn_mfma_f32_16x16x32_bf16(areg[mt][1], b1v, acc, 0, 0, 0);
      acc = __builtin_amdgcn_mfma_f32_16x16x32_bf16(areg[mt][2], b2v, acc, 0, 0, 0);
      float p0 = fmaxf(acc[0], acc[1]);
      float p1 = fmaxf(acc[2], acc[3]);
      float q0 = fmaxf(p0, __shfl_xor(p0, 32));
      float q1 = fmaxf(p1, __shfl_xor(p1, 32));
      if (quad < 2) {
        int p = mt * 4 + quad * 2;
        sc[p][c] = q0 + bias;
        sc[p + 1][c] = q1 + bias;
      }
    }
  }

  // ---- Phase A: Q + K GEMM (6 jobs/wave: w<3 -> 4Q+2K; w3 -> 6K) ----
#pragma unroll
  for (int aj = 0; aj < 6; ++aj) {
    int type, hh, nt;
    if (wave < 3) {
      if (aj < 4) { type = 0; hh = wave; nt = aj; }
      else { int kidx = wave * 2 + (aj - 4); type = 1; hh = kidx >> 2; nt = kidx & 3; }
    } else {
      int kidx = 6 + aj; type = 1; hh = kidx >> 2; nt = kidx & 3;
    }
    int gnt = type * 12 + hh * 4 + nt;
    const unsigned short* bp = qwp + (size_t)gnt * 1536 + lane * 8;
    bf16x8 b0 = *(const bf16x8*)(bp);
    bf16x8 b1v = *(const bf16x8*)(bp + 512);
    bf16x8 b2v = *(const bf16x8*)(bp + 1024);
    int dloc = nt * 16 + l15;
    int dglob = hh * 64 + dloc;
    float bias = qb[type * 192 + dglob];
#pragma unroll
    for (int mt = 0; mt < 4; ++mt) {
      f32x4 acc = {0.f, 0.f, 0.f, 0.f};
      acc = __builtin_amdgcn_mfma_f32_16x16x32_bf16(areg[mt][0], b0, acc, 0, 0, 0);
      acc = __builtin_amdgcn_mfma_f32_16x16x32_bf16(areg[mt][1], b1v, acc, 0, 0, 0);
      acc = __builtin_amdgcn_mfma_f32_16x16x32_bf16(areg[mt][2], b2v, acc, 0, 0, 0);
      if (type == 0) {
        float p0 = fmaxf(acc[0], acc[1]);
        float p1 = fmaxf(acc[2], acc[3]);
        float q0 = fmaxf(p0, __shfl_xor(p0, 32));
        float q1 = fmaxf(p1, __shfl_xor(p1, 32));
        if (quad < 2) {
          int p = mt * 4 + quad * 2;
          wbuf[wave][p][dloc] = f2bf(q0 + bias);  // pooled Q, wave-private
          wbuf[wave][p + 1][dloc] = f2bf(q1 + bias);
        }
      } else {
        int t0 = mt * 16 + quad * 4;
#pragma unroll
        for (int r = 0; r < 4; ++r) kk[t0 + r][dglob] = f2bf(acc[r] + bias);
      }
    }
  }
  __syncthreads();  // B1: K + pooled Q visible

  // ---- QK^T (wave h owns head h) ----
  f32x4 s4[4];
  if (wave < 3) {
    int h = wave;
    bf16x8 aq0 = *(const bf16x8*)(&wbuf[wave][l15][quad * 8]);
    bf16x8 aq1 = *(const bf16x8*)(&wbuf[wave][l15][32 + quad * 8]);
#pragma unroll
    for (int kt = 0; kt < 4; ++kt) {
      bf16x8 bk0 = *(const bf16x8*)(&kk[kt * 16 + l15][h * 64 + quad * 8]);
      bf16x8 bk1 = *(const bf16x8*)(&kk[kt * 16 + l15][h * 64 + 32 + quad * 8]);
      f32x4 s = {0.f, 0.f, 0.f, 0.f};
      s = __builtin_amdgcn_mfma_f32_16x16x32_bf16(aq0, bk0, s, 0, 0, 0);
      s = __builtin_amdgcn_mfma_f32_16x16x32_bf16(aq1, bk1, s, 0, 0, 0);
      s4[kt] = s;
    }
  }
  __syncthreads();  // B1.5: all K reads done -> V may overwrite buf1

  // ---- Phase B: V GEMM (3 jobs/wave, all waves) into vT ----
#pragma unroll
  for (int vj = 0; vj < 3; ++vj) {
    int vidx = wave * 3 + vj;
    int hh = vidx >> 2, nt = vidx & 3;
    const unsigned short* bp =
        qwp + (size_t)(24 + hh * 4 + nt) * 1536 + lane * 8;
    bf16x8 b0 = *(const bf16x8*)(bp);
    bf16x8 b1v = *(const bf16x8*)(bp + 512);
    bf16x8 b2v = *(const bf16x8*)(bp + 1024);
    int dglob = hh * 64 + nt * 16 + l15;
    float bias = qb[384 + dglob];
#pragma unroll
    for (int mt = 0; mt < 4; ++mt) {
      f32x4 acc = {0.f, 0.f, 0.f, 0.f};
      acc = __builtin_amdgcn_mfma_f32_16x16x32_bf16(areg[mt][0], b0, acc, 0, 0, 0);
      acc = __builtin_amdgcn_mfma_f32_16x16x32_bf16(areg[mt][1], b1v, acc, 0, 0, 0);
      acc = __builtin_amdgcn_mfma_f32_16x16x32_bf16(areg[mt][2], b2v, acc, 0, 0, 0);
      int t0 = mt * 16 + quad * 4;
      u16x4 pk;
#pragma unroll
      for (int r = 0; r < 4; ++r) pk[r] = f2bf(acc[r] + bias);
      *(u16x4*)(&vT[dglob][t0]) = pk;
    }
  }

  // ---- softmax (in-register) + P -> A-layout via wbuf ----
  if (wave < 3) {
    float ps[4][4];
#pragma unroll
    for (int r = 0; r < 4; ++r) {
      float m = fmaxf(fmaxf(s4[0][r], s4[1][r]), fmaxf(s4[2][r], s4[3][r]));
#pragma unroll
      for (int o = 8; o; o >>= 1) m = fmaxf(m, __shfl_xor(m, o));
      float sm = 0.f;
#pragma unroll
      for (int kt = 0; kt < 4; ++kt) {
        float e = __expf((s4[kt][r] - m) * 0.125f);
        ps[kt][r] = e;
        sm += e;
      }
#pragma unroll
      for (int o = 8; o; o >>= 1) sm += __shfl_xor(sm, o);
      float inv = __builtin_amdgcn_rcpf(sm);
#pragma unroll
      for (int kt = 0; kt < 4; ++kt) ps[kt][r] *= inv;
    }
#pragma unroll
    for (int kt = 0; kt < 4; ++kt)
#pragma unroll
      for (int r = 0; r < 4; ++r)
        wbuf[wave][quad * 4 + r][kt * 16 + l15] = f2bf(ps[kt][r]);
  }
  __syncthreads();  // B1.75: vT visible (and P stable)

  // ---- PV ----
  f32x4 o4[4];
  if (wave < 3) {
    int h = wave;
    bf16x8 ap0 = *(const bf16x8*)(&wbuf[wave][l15][quad * 8]);
    bf16x8 ap1 = *(const bf16x8*)(&wbuf[wave][l15][32 + quad * 8]);
#pragma unroll
    for (int dt = 0; dt < 4; ++dt) {
      bf16x8 bv0 = *(const bf16x8*)(&vT[h * 64 + dt * 16 + l15][quad * 8]);
      bf16x8 bv1 = *(const bf16x8*)(&vT[h * 64 + dt * 16 + l15][32 + quad * 8]);
      f32x4 o = {0.f, 0.f, 0.f, 0.f};
      o = __builtin_amdgcn_mfma_f32_16x16x32_bf16(ap0, bv0, o, 0, 0, 0);
      o = __builtin_amdgcn_mfma_f32_16x16x32_bf16(ap1, bv1, o, 0, 0, 0);
      o4[dt] = o;
    }
  }
  __syncthreads();  // B2: V reads done -> obb region writable

  if (wave < 3) {
    int h = wave;
#pragma unroll
    for (int dt = 0; dt < 4; ++dt)
#pragma unroll
      for (int r = 0; r < 4; ++r)
        kk[quad * 4 + r][h * 64 + dt * 16 + l15] = f2bf(o4[dt][r]);  // obb
  }
  __syncthreads();  // B3: obb readable

  // ---- attn_proj: O(16x192) @ aw + ab; y = shortcut + attn into sc ----
  bf16x8 ao[6];
#pragma unroll
  for (int ks = 0; ks < 6; ++ks)
    ao[ks] = *(const bf16x8*)(&kk[l15][ks * 32 + quad * 8]);
#pragma unroll
  for (int nl = 0; nl < 3; ++nl) {
    int ntl = wave * 3 + nl;
    const unsigned short* bp = awp + (size_t)ntl * 3072 + lane * 8;
    f32x4 acc = {0.f, 0.f, 0.f, 0.f};
#pragma unroll
    for (int ks = 0; ks < 6; ++ks) {
      bf16x8 bw = *(const bf16x8*)(bp + ks * 512);
      acc = __builtin_amdgcn_mfma_f32_16x16x32_bf16(ao[ks], bw, acc, 0, 0, 0);
    }
    int cc = ntl * 16 + l15;
    float bias = ab[cc];
#pragma unroll
    for (int r = 0; r < 4; ++r) {
      int p = quad * 4 + r;
      sc[p][cc] += acc[r] + bias;  // unique (p,cc) per thread
    }
  }
  __syncthreads();  // B4: y complete in sc

  // ---- LN2 on the 16 pooled tokens (16 lanes per token, 12 ch each) ----
  {
    int tt = wave * 4 + quad;  // 0..15
    const f32x4* y4 = (const f32x4*)(&sc[tt][l15 * 12]);
    f32x4 vv[3];
    vv[0] = y4[0]; vv[1] = y4[1]; vv[2] = y4[2];
    float s = 0.f;
#pragma unroll
    for (int i = 0; i < 3; ++i)
#pragma unroll
      for (int j = 0; j < 4; ++j) s += vv[i][j];
    s += __shfl_xor(s, 1);
    s += __shfl_xor(s, 2);
    s += __shfl_xor(s, 4);
    s += __shfl_xor(s, 8);
    float mean = s * (1.f / 192.f);
    float q = 0.f;
#pragma unroll
    for (int i = 0; i < 3; ++i)
#pragma unroll
      for (int j = 0; j < 4; ++j) {
        float d = vv[i][j] - mean;
        q += d * d;
      }
    q += __shfl_xor(q, 1);
    q += __shfl_xor(q, 2);
    q += __shfl_xor(q, 4);
    q += __shfl_xor(q, 8);
    float rstd = rsqrtf(q * (1.f / 192.f) + EPSV);
    const f32x4* g4 = (const f32x4*)(n2g + l15 * 12);
    const f32x4* b4 = (const f32x4*)(n2b + l15 * 12);
#pragma unroll
    for (int i = 0; i < 3; ++i) {
      f32x4 gg = g4[i], bb = b4[i];
      u16x4 o;
#pragma unroll
      for (int j = 0; j < 4; ++j)
        o[j] = f2bf((vv[i][j] - mean) * rstd * gg[j] + bb[j]);
      *(u16x4*)(&yn[tt][l15 * 12 + i * 4]) = o;
    }
  }
  __syncthreads();  // B5: yn ready

  // ---- MLP: 16x192 -> 768 (gelu) -> 192, 4 hidden chunks of 192 ----
  bf16x8 ar[6];
#pragma unroll
  for (int ks = 0; ks < 6; ++ks)
    ar[ks] = *(const bf16x8*)(&yn[l15][ks * 32 + quad * 8]);

  f32x4 acc2[3];
#pragma unroll
  for (int nl = 0; nl < 3; ++nl) acc2[nl] = (f32x4){0.f, 0.f, 0.f, 0.f};

  for (int c = 0; c < 4; ++c) {
#pragma unroll
    for (int nl = 0; nl < 3; ++nl) {
      int gnt = c * 12 + wave * 3 + nl;
      const unsigned short* bp = w1p + ((size_t)(gnt * 6) * 64 + lane) * 8;
      f32x4 t0 = {0.f, 0.f, 0.f, 0.f};
#pragma unroll
      for (int ks = 0; ks < 6; ++ks) {
        bf16x8 bw = *(const bf16x8*)(bp + ks * 512);
        t0 = __builtin_amdgcn_mfma_f32_16x16x32_bf16(ar[ks], bw, t0, 0, 0, 0);
      }
      int lcol = wave * 48 + nl * 16 + l15;
      float bias = b1[c * 192 + lcol];
#pragma unroll
      for (int r = 0; r < 4; ++r)
        hls[quad * 4 + r][lcol] = f2bf(fast_gelu(t0[r] + bias));
    }
    __syncthreads();  // hls chunk ready
    bf16x8 hr[6];
#pragma unroll
    for (int ks = 0; ks < 6; ++ks)
      hr[ks] = *(const bf16x8*)(&hls[l15][ks * 32 + quad * 8]);
#pragma unroll
    for (int nl = 0; nl < 3; ++nl) {
      int nt2 = wave * 3 + nl;
      const unsigned short* bp =
          w2p + ((size_t)(nt2 * 24 + c * 6) * 64 + lane) * 8;
#pragma unroll
      for (int ks = 0; ks < 6; ++ks) {
        bf16x8 bw = *(const bf16x8*)(bp + ks * 512);
        acc2[nl] =
            __builtin_amdgcn_mfma_f32_16x16x32_bf16(hr[ks], bw, acc2[nl], 0, 0, 0);
      }
    }
    __syncthreads();  // hls readers done -> next chunk may overwrite
  }

  // ---- epilogue: out = y + mlp + b2, pure store ----
#pragma unroll
  for (int nl = 0; nl < 3; ++nl) {
    int col = (wave * 3 + nl) * 16 + l15;
    float bias = b2[col];
#pragma unroll
    for (int r = 0; r < 4; ++r) {
      int p = quad * 4 + r;
      int hp = nh * 4 + (p >> 2), wp2 = nw * 4 + (p & 3);
      size_t oi = ((size_t)((b * 128 + hp) * 128 + wp2)) * 192 + col;
      out[oi] = sc[p][col] + acc2[nl][r] + bias;
    }
  }
}

extern "C" void kernel_launch(void* const* d_in, const int* in_sizes, int n_in,
                              void* d_out, int out_size, void* d_ws,
                              size_t ws_size, hipStream_t stream) {
  const float* x = (const float*)d_in[0];
  const float* n1g = (const float*)d_in[1];
  const float* n1b = (const float*)d_in[2];
  const float* pw = (const float*)d_in[3];
  const float* pb = (const float*)d_in[4];
  const float* qw = (const float*)d_in[5];
  const float* qb = (const float*)d_in[6];
  const float* aw = (const float*)d_in[7];
  const float* ab = (const float*)d_in[8];
  const float* n2g = (const float*)d_in[9];
  const float* n2b = (const float*)d_in[10];
  const float* w1 = (const float*)d_in[11];
  const float* b1 = (const float*)d_in[12];
  const float* w2 = (const float*)d_in[13];
  const float* b2 = (const float*)d_in[14];
  float* out = (float*)d_out;

  char* wsb = (char*)d_ws;
  unsigned short* qwp = (unsigned short*)wsb;               //    110,592 B
  unsigned short* awp = (unsigned short*)(wsb + 110592);    //     73,728 B
  unsigned short* w1p = (unsigned short*)(wsb + 184320);    //    294,912 B
  unsigned short* w2p = (unsigned short*)(wsb + 479232);    //    294,912 B
  unsigned short* pwp = (unsigned short*)(wsb + 774144);    //     36,864 B

  hipLaunchKernelGGL(k0_pack, dim3(198), dim3(256), 0, stream, qw, aw, w1, w2,
                     pw, qwp, awp, w1p, w2p, pwp);
  hipLaunchKernelGGL(k1234_fused, dim3(4096), dim3(256), 0, stream, x, n1g,
                     n1b, pwp, pb, qwp, qb, awp, ab, n2g, n2b, w1p, b1, w2p,
                     b2, out);
}